// Round 6
// baseline (543.346 us; speedup 1.0000x reference)
//
#include <hip/hip_runtime.h>
#include <math.h>

#define T_SEQ 4096
#define CEMB  1024
#define CHEAD 64
#define NB    8

typedef __attribute__((ext_vector_type(8))) short bf8;   // 8 bf16 (4 VGPRs)
typedef __attribute__((ext_vector_type(4))) short s4v;   // 4 bf16 (8B)
typedef __attribute__((ext_vector_type(4))) float f4;    // MFMA C/D

#define MFMA(a, b, c) __builtin_amdgcn_mfma_f32_16x16x32_bf16((a), (b), (c), 0, 0, 0)

__device__ __forceinline__ short f2bf(float f) {
    unsigned int u = __float_as_uint(f);
    u += 0x7fffu + ((u >> 16) & 1u);          // round-to-nearest-even
    return (short)(u >> 16);
}
__device__ __forceinline__ float bf2f(short h) {
    return __uint_as_float(((unsigned int)(unsigned short)h) << 16);
}

// ---------------------------------------------------------------------------
// Kernel 0: W -> plain transposed hi/lo bf16: Wt[2m+hl][h][c]  (m:0=Q 1=K 2=V)
// (L2-resident, 786 KB total; proj reads frags direct from global — no LDS)
// ---------------------------------------------------------------------------
__global__ __launch_bounds__(256) void wsplit_kernel(
    const float* __restrict__ Wk, const float* __restrict__ Wq,
    const float* __restrict__ Wv, short* __restrict__ Wt)
{
    int id = blockIdx.x * 256 + threadIdx.x;       // exactly 3*65536 threads
    int m = id >> 16;
    int rem = id & 65535;
    int c = rem >> 6, h = rem & 63;
    const float* W = (m == 0) ? Wq : (m == 1) ? Wk : Wv;
    float f = W[c * 64 + h];
    short hi = f2bf(f);
    short lo = f2bf(f - bf2f(hi));
    size_t base = (size_t)h * 1024 + c;
    Wt[(size_t)(2 * m) * 65536 + base]     = hi;
    Wt[(size_t)(2 * m + 1) * 65536 + base] = lo;
}

// ---------------------------------------------------------------------------
// Kernel 1: QKV projection, LDS-free.  2-term split (xh*(Wh+Wl)).
// 32-row tiles, grid 1024; 4 waves/block, wave w owns h-columns [16w,16w+16).
// All W frags direct from global (L2-hot); zero barriers.
// ---------------------------------------------------------------------------
__global__ __launch_bounds__(256, 4) void proj_kernel(
    const float* __restrict__ x, const short* __restrict__ Wt,
    short* __restrict__ Qhi, short* __restrict__ Qlo,
    short* __restrict__ Khi, short* __restrict__ Klo,
    short* __restrict__ VThi, short* __restrict__ VTlo)
{
    const int tid = threadIdx.x;
    const int lane = tid & 63, w = tid >> 6;       // w = h-quarter
    const int l15 = lane & 15, lg = lane >> 4;
    const int row0 = blockIdx.x * 32;

    f4 acc[3][2] = {};                             // [m][qf]
    const short* wbase = Wt + (size_t)(16 * w + l15) * 1024 + lg * 8;
    const float* xb0 = x + (size_t)(row0 + l15) * CEMB + lg * 8;
    const float* xb1 = x + (size_t)(row0 + 16 + l15) * CEMB + lg * 8;

    #pragma unroll 2
    for (int c = 0; c < 32; ++c) {
        bf8 xh[2];
        {
            float4 a0 = *reinterpret_cast<const float4*>(xb0 + c * 32);
            float4 a1 = *reinterpret_cast<const float4*>(xb0 + c * 32 + 4);
            float4 b0 = *reinterpret_cast<const float4*>(xb1 + c * 32);
            float4 b1 = *reinterpret_cast<const float4*>(xb1 + c * 32 + 4);
            const float* pa0 = reinterpret_cast<const float*>(&a0);
            const float* pa1 = reinterpret_cast<const float*>(&a1);
            const float* pb0 = reinterpret_cast<const float*>(&b0);
            const float* pb1 = reinterpret_cast<const float*>(&b1);
            #pragma unroll
            for (int e = 0; e < 4; ++e) {
                xh[0][e]     = f2bf(pa0[e]);
                xh[0][4 + e] = f2bf(pa1[e]);
                xh[1][e]     = f2bf(pb0[e]);
                xh[1][4 + e] = f2bf(pb1[e]);
            }
        }
        #pragma unroll
        for (int m = 0; m < 3; ++m) {
            bf8 wh = *reinterpret_cast<const bf8*>(wbase + (size_t)(2 * m) * 65536 + c * 32);
            bf8 wl = *reinterpret_cast<const bf8*>(wbase + (size_t)(2 * m + 1) * 65536 + c * 32);
            #pragma unroll
            for (int qf = 0; qf < 2; ++qf) {
                acc[m][qf] = MFMA(xh[qf], wh, acc[m][qf]);
                acc[m][qf] = MFMA(xh[qf], wl, acc[m][qf]);
            }
        }
    }

    const int hcol = 16 * w + l15;
    #pragma unroll
    for (int qf = 0; qf < 2; ++qf) {
        int qb = row0 + 16 * qf + 4 * lg;          // + r
        #pragma unroll
        for (int r = 0; r < 4; ++r) {
            float fq = acc[0][qf][r];
            short hq = f2bf(fq);
            Qhi[(size_t)(qb + r) * 64 + hcol] = hq;
            Qlo[(size_t)(qb + r) * 64 + hcol] = f2bf(fq - bf2f(hq));
            float fk = acc[1][qf][r];
            short hk = f2bf(fk);
            Khi[(size_t)(qb + r) * 64 + hcol] = hk;
            Klo[(size_t)(qb + r) * 64 + hcol] = f2bf(fk - bf2f(hk));
        }
        int bb = qb >> 12, t0 = qb & 4095;         // 32 | 4096: no spanning
        s4v vh, vl;
        #pragma unroll
        for (int r = 0; r < 4; ++r) {
            float fv = acc[2][qf][r];
            vh[r] = f2bf(fv);
            vl[r] = f2bf(fv - bf2f(vh[r]));
        }
        *reinterpret_cast<s4v*>(&VThi[((size_t)bb * 64 + hcol) * T_SEQ + t0]) = vh;
        *reinterpret_cast<s4v*>(&VTlo[((size_t)bb * 64 + hcol) * T_SEQ + t0]) = vl;
    }
}

// ---------------------------------------------------------------------------
// Kernel 2: column denominators, hi*hi only.  grid (64 ktiles, 4 qsplits, B).
// ---------------------------------------------------------------------------
__global__ __launch_bounds__(256, 4) void colsum_kernel(
    const short* __restrict__ Qhi, const short* __restrict__ Khi,
    float* __restrict__ Dp)
{
    __shared__ float red[4][64];
    const int tid = threadIdx.x;
    const int lane = tid & 63, w = tid >> 6;
    const int l15 = lane & 15, lg = lane >> 4;
    const int k0 = blockIdx.x * 64;
    const int qs = blockIdx.y, b = blockIdx.z;
    const size_t bT = (size_t)b * T_SEQ;

    bf8 kbh[4][2];
    #pragma unroll
    for (int kf = 0; kf < 4; ++kf)
        #pragma unroll
        for (int dc = 0; dc < 2; ++dc)
            kbh[kf][dc] = *reinterpret_cast<const bf8*>(
                Khi + (bT + k0 + 16 * kf + l15) * 64 + dc * 32 + lg * 8);
    float csum[4] = {0.f, 0.f, 0.f, 0.f};

    for (int q0 = k0 + qs * 128; q0 < T_SEQ; q0 += 512) {
        bf8 qah[2][2];
        #pragma unroll
        for (int qf = 0; qf < 2; ++qf)
            #pragma unroll
            for (int dc = 0; dc < 2; ++dc) {
                int row = q0 + w * 32 + 16 * qf + l15;
                row = row < T_SEQ ? row : T_SEQ - 1;
                qah[qf][dc] = *reinterpret_cast<const bf8*>(
                    Qhi + (bT + row) * 64 + dc * 32 + lg * 8);
            }
        f4 s[2][4] = {};
        #pragma unroll
        for (int dc = 0; dc < 2; ++dc)
            #pragma unroll
            for (int qf = 0; qf < 2; ++qf)
                #pragma unroll
                for (int kf = 0; kf < 4; ++kf)
                    s[qf][kf] = MFMA(qah[qf][dc], kbh[kf][dc], s[qf][kf]);
        #pragma unroll
        for (int qf = 0; qf < 2; ++qf)
            #pragma unroll
            for (int kf = 0; kf < 4; ++kf)
                #pragma unroll
                for (int r = 0; r < 4; ++r) {
                    int q = q0 + w * 32 + 16 * qf + lg * 4 + r;
                    int kc = k0 + 16 * kf + l15;
                    if (q >= kc && q < T_SEQ)
                        csum[kf] += __expf(s[qf][kf][r] * 0.125f);
                }
    }
    #pragma unroll
    for (int kf = 0; kf < 4; ++kf) {
        csum[kf] += __shfl_xor(csum[kf], 16);
        csum[kf] += __shfl_xor(csum[kf], 32);
    }
    if (lg == 0) {
        #pragma unroll
        for (int kf = 0; kf < 4; ++kf) red[w][16 * kf + l15] = csum[kf];
    }
    __syncthreads();
    if (tid < 64) {
        float d = red[0][tid] + red[1][tid] + red[2][tid] + red[3][tid];
        Dp[((size_t)qs * NB + b) * T_SEQ + k0 + tid] = d;
    }
}

// ---------------------------------------------------------------------------
// Kernel 3: Dinv = 1 / (sum of 4 Dp partials)
// ---------------------------------------------------------------------------
__global__ __launch_bounds__(256) void dinv_kernel(
    const float* __restrict__ Dp, float* __restrict__ Dinv)
{
    int i = blockIdx.x * 256 + threadIdx.x;        // 32768 threads
    const int S = NB * T_SEQ;
    float d = Dp[i] + Dp[S + i] + Dp[2 * S + i] + Dp[3 * S + i];
    Dinv[i] = 1.0f / d;
}

// ---------------------------------------------------------------------------
// Kernel 4: V~ = V / d   (fold softmax denominator into V, in place).
// O[q] = sum_k exp(s[q,k]) * (V[k]/d_k)  — normalizer depends only on k.
// ---------------------------------------------------------------------------
__global__ __launch_bounds__(256) void vscale_kernel(
    short* __restrict__ VThi, short* __restrict__ VTlo,
    const float* __restrict__ Dinv)
{
    int f = (blockIdx.x * 256 + threadIdx.x) * 4;  // 2048 blocks: f < 2,097,152
    int b = f >> 18;
    int t = f & 4095;                              // flat == (b*64+h)*4096+t
    s4v vh = *reinterpret_cast<const s4v*>(VThi + f);
    s4v vl = *reinterpret_cast<const s4v*>(VTlo + f);
    float4 di = *reinterpret_cast<const float4*>(Dinv + b * T_SEQ + t);
    const float* dip = reinterpret_cast<const float*>(&di);
    #pragma unroll
    for (int r = 0; r < 4; ++r) {
        float v = (bf2f(vh[r]) + bf2f(vl[r])) * dip[r];
        short nh = f2bf(v);
        vh[r] = nh;
        vl[r] = f2bf(v - bf2f(nh));
    }
    *reinterpret_cast<s4v*>(VThi + f) = vh;
    *reinterpret_cast<s4v*>(VTlo + f) = vl;
}

// ---------------------------------------------------------------------------
// Kernel 5: O = exp(S) @ V~.  R4 shape: 128-row q-tiles, 4 waves x 32 rows,
// 96 MFMA/iter/wave; 4-way interleaved k-split, grid 1024 (4 blk/CU);
// b = bid&7 pins batches to XCDs.  P hi-only via 2KB/wave swizzled LDS.
// Partials atomicAdd'ed into pre-zeroed d_out (no combine pass).
// ---------------------------------------------------------------------------
__global__ __launch_bounds__(256, 4) void out_kernel(
    const short* __restrict__ Qhi, const short* __restrict__ Qlo,
    const short* __restrict__ Khi, const short* __restrict__ Klo,
    const short* __restrict__ VThi, const short* __restrict__ VTlo,
    float* __restrict__ out)
{
    __shared__ short pt[4][2048];     // [wave][32 q rows x 64 k] hi-only P
    const int tid = threadIdx.x;
    const int lane = tid & 63, w = tid >> 6;
    const int l15 = lane & 15, lg = lane >> 4;
    const int bx = blockIdx.x;
    const int b   = bx & 7;                        // XCD-pinned batch
    const int qtr = (bx >> 3) & 31;
    const int ks  = bx >> 8;                       // 0..3
    const int qt  = (ks & 1) ? 31 - qtr : qtr;     // pairing for balance
    const int q0  = qt * 128;
    const size_t bT = (size_t)b * T_SEQ;
    short* ptw = pt[w];

    bf8 qh[2][2], ql[2][2];           // persistent Q frags [qf][dc]
    #pragma unroll
    for (int qf = 0; qf < 2; ++qf)
        #pragma unroll
        for (int dc = 0; dc < 2; ++dc) {
            size_t o = (bT + q0 + 32 * w + 16 * qf + l15) * 64 + dc * 32 + lg * 8;
            qh[qf][dc] = *reinterpret_cast<const bf8*>(Qhi + o);
            ql[qf][dc] = *reinterpret_cast<const bf8*>(Qlo + o);
        }
    f4 oacc[2][4] = {};

    for (int k0 = ks * 64; k0 < q0 + 128; k0 += 256) {
        // --- S^T = K · Q^T (3-term split) ---
        f4 st[4][2] = {};
        #pragma unroll
        for (int dc = 0; dc < 2; ++dc) {
            bf8 kh[4], kl[4];
            #pragma unroll
            for (int kf = 0; kf < 4; ++kf) {
                size_t o = (bT + k0 + 16 * kf + l15) * 64 + dc * 32 + lg * 8;
                kh[kf] = *reinterpret_cast<const bf8*>(Khi + o);
                kl[kf] = *reinterpret_cast<const bf8*>(Klo + o);
            }
            #pragma unroll
            for (int kf = 0; kf < 4; ++kf)
                #pragma unroll
                for (int qf = 0; qf < 2; ++qf) {
                    st[kf][qf] = MFMA(kh[kf], qh[qf][dc], st[kf][qf]);
                    st[kf][qf] = MFMA(kh[kf], ql[qf][dc], st[kf][qf]);
                    st[kf][qf] = MFMA(kl[kf], qh[qf][dc], st[kf][qf]);
                }
        }
        // --- P = exp(S) (hi-only; 1/d is folded into V~) ---
        #pragma unroll
        for (int kf = 0; kf < 4; ++kf)
            #pragma unroll
            for (int qf = 0; qf < 2; ++qf) {
                int qloc = 16 * qf + l15;
                int q = q0 + 32 * w + qloc;
                unsigned short hb[4];
                #pragma unroll
                for (int r = 0; r < 4; ++r) {
                    int kg = k0 + 16 * kf + 4 * lg + r;
                    float p = (q >= kg) ? __expf(st[kf][qf][r] * 0.125f) : 0.f;
                    hb[r] = (unsigned short)f2bf(p);
                }
                int sidx = qloc * 64 + (((16 * kf + 4 * lg) ^ ((qloc & 7) << 3)));
                *reinterpret_cast<int2*>(&ptw[sidx]) = make_int2(
                    (int)((unsigned)hb[0] | ((unsigned)hb[1] << 16)),
                    (int)((unsigned)hb[2] | ((unsigned)hb[3] << 16)));
            }
        // --- PV: O += P · V~ (P hi x (V hi + V lo)) ---
        #pragma unroll
        for (int kb = 0; kb < 2; ++kb) {
            bf8 vh[4], vl[4];
            #pragma unroll
            for (int hf = 0; hf < 4; ++hf) {
                size_t o = ((size_t)b * 64 + 16 * hf + l15) * T_SEQ
                         + k0 + 32 * kb + 8 * lg;
                vh[hf] = *reinterpret_cast<const bf8*>(VThi + o);
                vl[hf] = *reinterpret_cast<const bf8*>(VTlo + o);
            }
            #pragma unroll
            for (int qf = 0; qf < 2; ++qf) {
                int qloc = 16 * qf + l15;
                int ridx = qloc * 64 + (((32 * kb + 8 * lg) ^ ((qloc & 7) << 3)));
                bf8 pa = *reinterpret_cast<const bf8*>(&ptw[ridx]);
                #pragma unroll
                for (int hf = 0; hf < 4; ++hf) {
                    oacc[qf][hf] = MFMA(pa, vh[hf], oacc[qf][hf]);
                    oacc[qf][hf] = MFMA(pa, vl[hf], oacc[qf][hf]);
                }
            }
        }
    }
    #pragma unroll
    for (int qf = 0; qf < 2; ++qf)
        #pragma unroll
        for (int hf = 0; hf < 4; ++hf)
            #pragma unroll
            for (int r = 0; r < 4; ++r) {
                int q = q0 + 32 * w + 16 * qf + 4 * lg + r;
                atomicAdd(&out[(bT + q) * 64 + 16 * hf + l15], oacc[qf][hf][r]);
            }
}

extern "C" void kernel_launch(void* const* d_in, const int* in_sizes, int n_in,
                              void* d_out, int out_size, void* d_ws, size_t ws_size,
                              hipStream_t stream) {
    (void)in_sizes; (void)n_in; (void)ws_size;
    const float* x  = (const float*)d_in[0];
    const float* Wk = (const float*)d_in[1];
    const float* Wq = (const float*)d_in[2];
    const float* Wv = (const float*)d_in[3];
    float* out = (float*)d_out;
    char* w8 = (char*)d_ws;

    const size_t SZ = (size_t)NB * T_SEQ * CHEAD * sizeof(short);  // 4 MB
    short* Qhi  = (short*)(w8);
    short* Qlo  = (short*)(w8 + SZ);
    short* Khi  = (short*)(w8 + 2 * SZ);
    short* Klo  = (short*)(w8 + 3 * SZ);
    short* VThi = (short*)(w8 + 4 * SZ);
    short* VTlo = (short*)(w8 + 5 * SZ);
    short* Wt   = (short*)(w8 + 6 * SZ);                   // 786,432 B
    float* Dp   = (float*)(w8 + 6 * SZ + 786432);          // 524,288 B
    float* Dinv = (float*)(w8 + 6 * SZ + 786432 + 524288); // 131,072 B
    // total ws use ≈ 25.6 MB

    hipMemsetAsync(d_out, 0, (size_t)out_size * sizeof(float), stream);
    hipLaunchKernelGGL(wsplit_kernel, dim3(768), dim3(256), 0, stream,
                       Wk, Wq, Wv, Wt);
    hipLaunchKernelGGL(proj_kernel, dim3(1024), dim3(256), 0, stream,
                       x, Wt, Qhi, Qlo, Khi, Klo, VThi, VTlo);
    hipLaunchKernelGGL(colsum_kernel, dim3(64, 4, NB), dim3(256), 0, stream,
                       Qhi, Khi, Dp);
    hipLaunchKernelGGL(dinv_kernel, dim3(128), dim3(256), 0, stream,
                       Dp, Dinv);
    hipLaunchKernelGGL(vscale_kernel, dim3(2048), dim3(256), 0, stream,
                       VThi, VTlo, Dinv);
    hipLaunchKernelGGL(out_kernel, dim3(1024), dim3(256), 0, stream,
                       Qhi, Qlo, Khi, Klo, VThi, VTlo, out);
}

// Round 8
// 343.527 us; speedup vs baseline: 1.5817x; 1.5817x over previous
//
#include <hip/hip_runtime.h>
#include <math.h>

#define T_SEQ 4096
#define CEMB  1024
#define CHEAD 64
#define NB    8

typedef __attribute__((ext_vector_type(8))) short bf8;   // 8 bf16 (4 VGPRs)
typedef __attribute__((ext_vector_type(4))) short s4v;   // 4 bf16 (8B)
typedef __attribute__((ext_vector_type(4))) float f4;    // MFMA C/D

#define MFMA(a, b, c) __builtin_amdgcn_mfma_f32_16x16x32_bf16((a), (b), (c), 0, 0, 0)

__device__ __forceinline__ short f2bf(float f) {
    unsigned int u = __float_as_uint(f);
    u += 0x7fffu + ((u >> 16) & 1u);          // round-to-nearest-even
    return (short)(u >> 16);
}
__device__ __forceinline__ float bf2f(short h) {
    return __uint_as_float(((unsigned int)(unsigned short)h) << 16);
}

// ---------------------------------------------------------------------------
// Kernel 0: W -> hi/lo bf16 split, chunk-major XOR-swizzled layout (R5):
// Wp[c>>5][2m+hl][h][ (c&31) ^ (((h>>1)&3)<<3) ]
// ---------------------------------------------------------------------------
__global__ __launch_bounds__(256) void wsplit_kernel(
    const float* __restrict__ Wk, const float* __restrict__ Wq,
    const float* __restrict__ Wv, short* __restrict__ Wp)
{
    int id = blockIdx.x * 256 + threadIdx.x;       // exactly 3*65536 threads
    int m = id >> 16;
    int rem = id & 65535;
    int c = rem >> 6, h = rem & 63;
    const float* W = (m == 0) ? Wq : (m == 1) ? Wk : Wv;
    float f = W[c * 64 + h];
    short hi = f2bf(f);
    short lo = f2bf(f - bf2f(hi));
    int cs = (c & 31) ^ (((h >> 1) & 3) << 3);
    size_t base = ((size_t)(c >> 5) * 6) * 2048 + (size_t)h * 32 + cs;
    Wp[base + (size_t)(2 * m) * 2048]     = hi;
    Wp[base + (size_t)(2 * m + 1) * 2048] = lo;
}

// ---------------------------------------------------------------------------
// Kernel 1: QKV projection (R5 structure: dbuf W via global_load_lds,
// 2-term xh*(Wh+Wl), 4 waves x 16 rows, grid 512).
// Outputs: Qhi, Khi (hi only — all consumers are hi-only now), VThi/VTlo.
// ---------------------------------------------------------------------------
__global__ __launch_bounds__(256) void proj_kernel(
    const float* __restrict__ x, const short* __restrict__ Wp,
    short* __restrict__ Qhi, short* __restrict__ Khi,
    short* __restrict__ VThi, short* __restrict__ VTlo)
{
    __shared__ short wbuf[2][12288];               // 2 x 24KB
    const int tid = threadIdx.x;
    const int lane = tid & 63, w = tid >> 6;       // w in 0..3
    const int l15 = lane & 15, lg = lane >> 4;
    const int row0 = blockIdx.x * 64;

    f4 acc[3][4] = {};
    float4 xrA[2], xrB[2];

    auto stage = [&](int c, int buf) {
        const short* src = Wp + (size_t)c * 12288 + tid * 8;
        #pragma unroll
        for (int p = 0; p < 6; ++p) {
            __builtin_amdgcn_global_load_lds(
                (const __attribute__((address_space(1))) void*)(src + p * 2048),
                (__attribute__((address_space(3))) void*)&wbuf[buf][tid * 8 + p * 2048],
                16, 0, 0);
        }
    };
    auto xload = [&](int c, float4 (&xr)[2]) {
        const float* px = x + (size_t)(row0 + 16 * w + l15) * CEMB + c * 32 + lg * 8;
        xr[0] = *reinterpret_cast<const float4*>(px);
        xr[1] = *reinterpret_cast<const float4*>(px + 4);
    };
    const int swz = ((l15 >> 1) & 3) << 3;
    auto compute = [&](const float4 (&xr)[2], int buf) {
        bf8 xh;
        #pragma unroll
        for (int hv = 0; hv < 2; ++hv) {
            const float* fp = reinterpret_cast<const float*>(&xr[hv]);
            #pragma unroll
            for (int e = 0; e < 4; ++e) xh[hv * 4 + e] = f2bf(fp[e]);
        }
        #pragma unroll
        for (int m = 0; m < 3; ++m)
            #pragma unroll
            for (int hf = 0; hf < 4; ++hf) {
                int h = 16 * hf + l15;
                const short* bp = &wbuf[buf][(2 * m) * 2048 + h * 32 + ((lg << 3) ^ swz)];
                bf8 wh = *reinterpret_cast<const bf8*>(bp);
                bf8 wl = *reinterpret_cast<const bf8*>(bp + 2048);
                acc[m][hf] = MFMA(xh, wh, acc[m][hf]);
                acc[m][hf] = MFMA(xh, wl, acc[m][hf]);
            }
    };

    stage(0, 0);
    xload(0, xrA);
    __syncthreads();
    for (int c = 0; c < 32; c += 2) {
        stage(c + 1, 1);
        xload(c + 1, xrB);
        compute(xrA, 0);
        __syncthreads();
        if (c + 2 < 32) { stage(c + 2, 0); xload(c + 2, xrA); }
        compute(xrB, 1);
        __syncthreads();
    }

    #pragma unroll
    for (int hf = 0; hf < 4; ++hf) {
        int hcol = 16 * hf + l15;
        int qb = row0 + 16 * w + lg * 4;              // + r
        #pragma unroll
        for (int r = 0; r < 4; ++r) {
            Qhi[(size_t)(qb + r) * 64 + hcol] = f2bf(acc[0][hf][r]);
            Khi[(size_t)(qb + r) * 64 + hcol] = f2bf(acc[1][hf][r]);
        }
        int bb = qb >> 12, t0 = qb & 4095;
        s4v vh, vl;
        #pragma unroll
        for (int r = 0; r < 4; ++r) {
            float fv = acc[2][hf][r];
            vh[r] = f2bf(fv);
            vl[r] = f2bf(fv - bf2f(vh[r]));
        }
        *reinterpret_cast<s4v*>(&VThi[((size_t)bb * 64 + hcol) * T_SEQ + t0]) = vh;
        *reinterpret_cast<s4v*>(&VTlo[((size_t)bb * 64 + hcol) * T_SEQ + t0]) = vl;
    }
}

// ---------------------------------------------------------------------------
// Kernel 2: column denominators, hi*hi only.  8 q-splits for occupancy:
// grid (64 ktiles, 8 qsplits, B).  Same arithmetic as out_kernel's QK^T,
// so the softmax is exact-softmax-of-perturbed-scores (errors cancel).
// ---------------------------------------------------------------------------
__global__ __launch_bounds__(256, 4) void colsum_kernel(
    const short* __restrict__ Qhi, const short* __restrict__ Khi,
    float* __restrict__ Dp)
{
    __shared__ float red[4][64];
    const int tid = threadIdx.x;
    const int lane = tid & 63, w = tid >> 6;
    const int l15 = lane & 15, lg = lane >> 4;
    const int k0 = blockIdx.x * 64;
    const int qs = blockIdx.y, b = blockIdx.z;
    const size_t bT = (size_t)b * T_SEQ;

    bf8 kbh[4][2];
    #pragma unroll
    for (int kf = 0; kf < 4; ++kf)
        #pragma unroll
        for (int dc = 0; dc < 2; ++dc)
            kbh[kf][dc] = *reinterpret_cast<const bf8*>(
                Khi + (bT + k0 + 16 * kf + l15) * 64 + dc * 32 + lg * 8);
    float csum[4] = {0.f, 0.f, 0.f, 0.f};

    for (int q0 = k0 + qs * 128; q0 < T_SEQ; q0 += 1024) {
        bf8 qah[2][2];
        #pragma unroll
        for (int qf = 0; qf < 2; ++qf)
            #pragma unroll
            for (int dc = 0; dc < 2; ++dc) {
                int row = q0 + w * 32 + 16 * qf + l15;
                row = row < T_SEQ ? row : T_SEQ - 1;
                qah[qf][dc] = *reinterpret_cast<const bf8*>(
                    Qhi + (bT + row) * 64 + dc * 32 + lg * 8);
            }
        f4 s[2][4] = {};
        #pragma unroll
        for (int dc = 0; dc < 2; ++dc)
            #pragma unroll
            for (int qf = 0; qf < 2; ++qf)
                #pragma unroll
                for (int kf = 0; kf < 4; ++kf)
                    s[qf][kf] = MFMA(qah[qf][dc], kbh[kf][dc], s[qf][kf]);
        #pragma unroll
        for (int qf = 0; qf < 2; ++qf)
            #pragma unroll
            for (int kf = 0; kf < 4; ++kf)
                #pragma unroll
                for (int r = 0; r < 4; ++r) {
                    int q = q0 + w * 32 + 16 * qf + lg * 4 + r;
                    int kc = k0 + 16 * kf + l15;
                    if (q >= kc && q < T_SEQ)
                        csum[kf] += __expf(s[qf][kf][r] * 0.125f);
                }
    }
    #pragma unroll
    for (int kf = 0; kf < 4; ++kf) {
        csum[kf] += __shfl_xor(csum[kf], 16);
        csum[kf] += __shfl_xor(csum[kf], 32);
    }
    if (lg == 0) {
        #pragma unroll
        for (int kf = 0; kf < 4; ++kf) red[w][16 * kf + l15] = csum[kf];
    }
    __syncthreads();
    if (tid < 64) {
        float d = red[0][tid] + red[1][tid] + red[2][tid] + red[3][tid];
        Dp[((size_t)qs * NB + b) * T_SEQ + k0 + tid] = d;
    }
}

// ---------------------------------------------------------------------------
// Kernel 3: V~ = (Vhi+Vlo)/d  (dinv fused; result hi-only, in-place VThi).
// O[q] = sum_k exp(s[q,k]) * V~[k]  — normalizer depends only on k.
// ---------------------------------------------------------------------------
__global__ __launch_bounds__(256) void vscale_kernel(
    short* __restrict__ VThi, const short* __restrict__ VTlo,
    const float* __restrict__ Dp)
{
    int f = (blockIdx.x * 256 + threadIdx.x) * 4;  // 2048 blocks
    int b = f >> 18;
    int t = f & 4095;                              // flat == (b*64+h)*4096+t
    float d[4] = {0.f, 0.f, 0.f, 0.f};
    #pragma unroll
    for (int qs = 0; qs < 8; ++qs) {
        float4 dp = *reinterpret_cast<const float4*>(
            Dp + ((size_t)qs * NB + b) * T_SEQ + t);
        d[0] += dp.x; d[1] += dp.y; d[2] += dp.z; d[3] += dp.w;
    }
    s4v vh = *reinterpret_cast<const s4v*>(VThi + f);
    s4v vl = *reinterpret_cast<const s4v*>(VTlo + f);
    #pragma unroll
    for (int r = 0; r < 4; ++r)
        vh[r] = f2bf((bf2f(vh[r]) + bf2f(vl[r])) / d[r]);
    *reinterpret_cast<s4v*>(VThi + f) = vh;
}

// ---------------------------------------------------------------------------
// Kernel 4: O = exp(S) @ V~.  128-row q-tiles, 4 waves x 32 rows.
// QK^T hi*hi (IDENTICAL arithmetic to colsum -> consistent softmax);
// PV = P_hi x V~_hi (1/d folded).  6-way interleaved k-split, grid 1536
// (6 blk/CU); b = bid&7 pins batches to XCDs.  ks=0 writes fp32 to out,
// ks>=1 write bf16 partials (no atomics).  Zero barriers in the k-loop.
// ---------------------------------------------------------------------------
__global__ __launch_bounds__(256, 4) void out_kernel(
    const short* __restrict__ Qhi, const short* __restrict__ Khi,
    const short* __restrict__ VThi,
    float* __restrict__ out, short* __restrict__ Opart)
{
    __shared__ short pt[4][2048];     // [wave][32 q rows x 64 k] hi-only P
    const int tid = threadIdx.x;
    const int lane = tid & 63, w = tid >> 6;
    const int l15 = lane & 15, lg = lane >> 4;
    const int bx = blockIdx.x;
    const int b   = bx & 7;                        // XCD-pinned batch
    const int qtr = (bx >> 3) & 31;
    const int ks  = bx >> 8;                       // 0..5
    const int qt  = (ks & 1) ? 31 - qtr : qtr;     // pairing for balance
    const int q0  = qt * 128;
    const size_t bT = (size_t)b * T_SEQ;
    short* ptw = pt[w];

    bf8 qh[2][2];                     // persistent Q frags [qf][dc]
    #pragma unroll
    for (int qf = 0; qf < 2; ++qf)
        #pragma unroll
        for (int dc = 0; dc < 2; ++dc)
            qh[qf][dc] = *reinterpret_cast<const bf8*>(
                Qhi + (bT + q0 + 32 * w + 16 * qf + l15) * 64 + dc * 32 + lg * 8);
    f4 oacc[2][4] = {};

    for (int k0 = ks * 64; k0 < q0 + 128; k0 += 384) {
        // --- K loads (hi only) + early V~ prefetch for kb=0 ---
        bf8 kh[4][2];
        #pragma unroll
        for (int kf = 0; kf < 4; ++kf)
            #pragma unroll
            for (int dc = 0; dc < 2; ++dc)
                kh[kf][dc] = *reinterpret_cast<const bf8*>(
                    Khi + (bT + k0 + 16 * kf + l15) * 64 + dc * 32 + lg * 8);
        bf8 vh0[4];
        #pragma unroll
        for (int hf = 0; hf < 4; ++hf)
            vh0[hf] = *reinterpret_cast<const bf8*>(
                VThi + ((size_t)b * 64 + 16 * hf + l15) * T_SEQ + k0 + 8 * lg);
        // --- S^T = Khi · Qhi^T ---
        f4 st[4][2] = {};
        #pragma unroll
        for (int dc = 0; dc < 2; ++dc)
            #pragma unroll
            for (int kf = 0; kf < 4; ++kf)
                #pragma unroll
                for (int qf = 0; qf < 2; ++qf)
                    st[kf][qf] = MFMA(kh[kf][dc], qh[qf][dc], st[kf][qf]);
        // --- P = exp(S) (hi-only; 1/d folded into V~), swizzled LDS ---
        #pragma unroll
        for (int kf = 0; kf < 4; ++kf)
            #pragma unroll
            for (int qf = 0; qf < 2; ++qf) {
                int qloc = 16 * qf + l15;
                int q = q0 + 32 * w + qloc;
                unsigned short hb[4];
                #pragma unroll
                for (int r = 0; r < 4; ++r) {
                    int kg = k0 + 16 * kf + 4 * lg + r;
                    float p = (q >= kg) ? __expf(st[kf][qf][r] * 0.125f) : 0.f;
                    hb[r] = (unsigned short)f2bf(p);
                }
                int sidx = qloc * 64 + (((16 * kf + 4 * lg) ^ ((qloc & 7) << 3)));
                *reinterpret_cast<int2*>(&ptw[sidx]) = make_int2(
                    (int)((unsigned)hb[0] | ((unsigned)hb[1] << 16)),
                    (int)((unsigned)hb[2] | ((unsigned)hb[3] << 16)));
            }
        // --- PV: O += P_hi · V~_hi ---
        bf8 vh1[4];
        #pragma unroll
        for (int hf = 0; hf < 4; ++hf)
            vh1[hf] = *reinterpret_cast<const bf8*>(
                VThi + ((size_t)b * 64 + 16 * hf + l15) * T_SEQ + k0 + 32 + 8 * lg);
        #pragma unroll
        for (int qf = 0; qf < 2; ++qf) {
            int qloc = 16 * qf + l15;
            int r0 = qloc * 64 + (((8 * lg) ^ ((qloc & 7) << 3)));
            int r1 = qloc * 64 + (((32 + 8 * lg) ^ ((qloc & 7) << 3)));
            bf8 pa0 = *reinterpret_cast<const bf8*>(&ptw[r0]);
            bf8 pa1 = *reinterpret_cast<const bf8*>(&ptw[r1]);
            #pragma unroll
            for (int hf = 0; hf < 4; ++hf) {
                oacc[qf][hf] = MFMA(pa0, vh0[hf], oacc[qf][hf]);
                oacc[qf][hf] = MFMA(pa1, vh1[hf], oacc[qf][hf]);
            }
        }
    }
    if (ks == 0) {
        #pragma unroll
        for (int qf = 0; qf < 2; ++qf)
            #pragma unroll
            for (int hf = 0; hf < 4; ++hf)
                #pragma unroll
                for (int r = 0; r < 4; ++r) {
                    int q = q0 + 32 * w + 16 * qf + 4 * lg + r;
                    out[(bT + q) * 64 + 16 * hf + l15] = oacc[qf][hf][r];
                }
    } else {
        short* dst = Opart + (size_t)(ks - 1) * NB * T_SEQ * CHEAD;
        #pragma unroll
        for (int qf = 0; qf < 2; ++qf)
            #pragma unroll
            for (int hf = 0; hf < 4; ++hf)
                #pragma unroll
                for (int r = 0; r < 4; ++r) {
                    int q = q0 + 32 * w + 16 * qf + 4 * lg + r;
                    dst[(bT + q) * 64 + 16 * hf + l15] = f2bf(oacc[qf][hf][r]);
                }
    }
}

// ---------------------------------------------------------------------------
// Kernel 5: out += sum of 5 bf16 partials (deterministic combine)
// ---------------------------------------------------------------------------
__global__ __launch_bounds__(256) void combine_kernel(
    float* __restrict__ out, const short* __restrict__ Opart)
{
    const size_t N = (size_t)NB * T_SEQ * CHEAD;
    size_t i = ((size_t)blockIdx.x * 256 + threadIdx.x) * 4;
    float4 a = *reinterpret_cast<const float4*>(out + i);
    #pragma unroll
    for (int s = 0; s < 5; ++s) {
        s4v p = *reinterpret_cast<const s4v*>(Opart + s * N + i);
        a.x += bf2f(p[0]); a.y += bf2f(p[1]);
        a.z += bf2f(p[2]); a.w += bf2f(p[3]);
    }
    *reinterpret_cast<float4*>(out + i) = a;
}

extern "C" void kernel_launch(void* const* d_in, const int* in_sizes, int n_in,
                              void* d_out, int out_size, void* d_ws, size_t ws_size,
                              hipStream_t stream) {
    (void)in_sizes; (void)n_in; (void)out_size; (void)ws_size;
    const float* x  = (const float*)d_in[0];
    const float* Wk = (const float*)d_in[1];
    const float* Wq = (const float*)d_in[2];
    const float* Wv = (const float*)d_in[3];
    float* out = (float*)d_out;
    char* w8 = (char*)d_ws;

    const size_t SZ = (size_t)NB * T_SEQ * CHEAD * sizeof(short);  // 4 MB
    short* Qhi  = (short*)(w8);
    short* Khi  = (short*)(w8 + SZ);
    short* VThi = (short*)(w8 + 2 * SZ);
    short* VTlo = (short*)(w8 + 3 * SZ);
    short* Wp   = (short*)(w8 + 4 * SZ);                    // 786,432 B
    float* Dp   = (float*)(w8 + 4 * SZ + 786432);           // 1,048,576 B
    short* Opart= (short*)(w8 + 4 * SZ + 786432 + 1048576); // 5 x 4 MB
    // total ws use ≈ 37.8 MB (< 42.5 MB proven in round 1)

    hipLaunchKernelGGL(wsplit_kernel, dim3(768), dim3(256), 0, stream,
                       Wk, Wq, Wv, Wp);
    hipLaunchKernelGGL(proj_kernel, dim3(512), dim3(256), 0, stream,
                       x, Wp, Qhi, Khi, VThi, VTlo);
    hipLaunchKernelGGL(colsum_kernel, dim3(64, 8, NB), dim3(256), 0, stream,
                       Qhi, Khi, Dp);
    hipLaunchKernelGGL(vscale_kernel, dim3(2048), dim3(256), 0, stream,
                       VThi, VTlo, Dp);
    hipLaunchKernelGGL(out_kernel, dim3(1536), dim3(256), 0, stream,
                       Qhi, Khi, VThi, out, Opart);
    hipLaunchKernelGGL(combine_kernel, dim3(2048), dim3(256), 0, stream,
                       out, Opart);
}